// Round 16
// baseline (257.255 us; speedup 1.0000x reference)
//
#include <hip/hip_runtime.h>
#include <hip/hip_cooperative_groups.h>
#include <math.h>

namespace cg = cooperative_groups;

#define BATCH 2
#define NPTS  1024
#define NC    32
#define DIN   8
#define DOUT  8
#define ATILE 64                          // a's per block (4 waves x 16)
#define NCHUNK 16                         // b-splits
#define BPW   (NPTS / NCHUNK)             // 64 b's per block
#define GRP   8                           // pipeline group size
#define NGRP  (BPW / GRP)                 // 8 groups
#define OUT_ELEMS (BATCH * NPTS * DOUT)   // 16384
#define NE4   (OUT_ELEMS / 4)             // 4096
#define NBLK  512                         // 2 blocks/CU, coop co-resident
#define LOG2E 1.4426950408889634f
#define G_BYTES ((size_t)BATCH * NPTS * 64 * 16)   // 2 MB of half8 B-frags

typedef _Float16 half8 __attribute__((ext_vector_type(8)));
typedef __fp16   fp16x2 __attribute__((ext_vector_type(2)));
typedef float    floatx4 __attribute__((ext_vector_type(4)));

#if __has_builtin(__builtin_amdgcn_exp2f)
#define EXP2F(x) __builtin_amdgcn_exp2f(x)
#else
#define EXP2F(x) exp2f(x)
#endif

// ---------------------------------------------------------------------------
// fused: R16. All prior micro-variants left conv at ~30us with Occupancy~17%
// (~1.4 waves/SIMD) despite ample block supply — a grid-level residency /
// dispatch-trickle signature, not a per-wave stall (no within-wave model
// reproduces 560 cyc/iter). Cooperative launch guarantees all 512 blocks
// resident from t=0 and removes 2 dispatch boundaries.
//   phase 1: g B-frag build (1 slot/thread, 512*256 = 131072 slots exactly)
//   phase 2: conv — R15's spill-free register-pipelined body (verified)
//   phase 3: reduce — first 256 blocks, R15 body (verified)
// __threadfence() before each grid.sync() for cross-XCD visibility (G16).
// ---------------------------------------------------------------------------
__global__ __launch_bounds__(256, 2) void fused(
        const float* __restrict__ feat,
        const float* __restrict__ geo,
        const float* __restrict__ W,
        const int*   __restrict__ n_norm,
        float*       __restrict__ out,
        half8*       __restrict__ gws,
        float*       __restrict__ partial) {
    const int t   = threadIdx.x;
    const int bid = blockIdx.x;

    // ================= phase 1: build g B-frags =================
    {
        const int e    = bid * 256 + t;            // < BATCH*NPTS*64
        const int slot = e & 63;
        const int zb   = e >> 6;
        half8 gv = {};
        if (!(slot & 8)) {                         // n>=8 half stays zero
            const int i   = slot & 7;
            const int oct = slot >> 4;
            const float* f = feat + (size_t)zb * DIN;
            const float4 f0 = *(const float4*)f;
            const float4 f1 = *(const float4*)(f + 4);
#pragma unroll
            for (int j = 0; j < 8; ++j) {
                const float* wr = W + ((oct * 8 + j) * DOUT + i) * DIN;
                const float4 wa = *(const float4*)wr;
                const float4 wb = *(const float4*)(wr + 4);
                float s = fmaf(wa.x, f0.x,
                          fmaf(wa.y, f0.y,
                          fmaf(wa.z, f0.z,
                          fmaf(wa.w, f0.w,
                          fmaf(wb.x, f1.x,
                          fmaf(wb.y, f1.y,
                          fmaf(wb.z, f1.z,
                                 wb.w * f1.w)))))));
                gv[j] = (_Float16)s;
            }
        }
        gws[e] = gv;
    }
    __threadfence();
    cg::this_grid().sync();

    // ================= phase 2: conv (R15 body) =================
    {
        const int chunk = bid & (NCHUNK - 1);
        const int atile = (bid >> 4) & 15;
        const int z     = bid >> 8;

        const int b0 = chunk * BPW;
        const float* geoz = geo + (size_t)z * NPTS * 3;
        const float* bge  = geoz + b0 * 3;         // wave-uniform base

        const int lane = t & 63;
        const int wv   = t >> 6;
        const int m    = lane & 15;
        const int quad = lane >> 4;
        const int a0   = atile * ATILE + wv * 16;
        const int a    = a0 + m;

        const float ax = geoz[a * 3 + 0];
        const float ay = geoz[a * 3 + 1];
        const float az = geoz[a * 3 + 2];
        const float c0   = (float)(quad * 8);
        const float invw = (float)(NC - 1) / 3.5f;
        const float K2   = 0.13533528324f;         // exp(-2)
        const float K8   = 3.35462627903e-4f;      // exp(-8)

        const half8* gp = gws + ((size_t)(z * NPTS + b0)) * 64 + lane;

        floatx4 acc0 = {0.f, 0.f, 0.f, 0.f};
        floatx4 acc1 = {0.f, 0.f, 0.f, 0.f};

        auto compute_grp = [&](int g, const half8* buf) {
            const float* bg = bge + g * GRP * 3;
#pragma unroll
            for (int j = 0; j < GRP; ++j) {
                const float bx = bg[j * 3 + 0];
                const float by = bg[j * 3 + 1];
                const float bz = bg[j * 3 + 2];
                const float dx = bx - ax, dy = by - ay, dz = bz - az;
                const float u  = sqrtf(fmaf(dx, dx, fmaf(dy, dy, fmaf(dz, dz, 1e-12f)))) * invw;
                const float tc = fminf(u - c0, 11.0f);
                const float e0 = EXP2F((tc * tc) * (-LOG2E));
                const float t4 = tc - 4.0f;
                const float e4 = EXP2F((t4 * t4) * (-LOG2E));
                const float r0 = EXP2F(fmaf(2.0f * LOG2E, tc, -LOG2E));  // exp(2tc-1)
                const float r4 = r0 * K8;
                const float e1 = e0 * r0;  const float r1 = r0 * K2;
                const float e2 = e1 * r1;  const float r2 = r1 * K2;
                const float e3 = e2 * r2;
                const float e5 = e4 * r4;  const float r5 = r4 * K2;
                const float e6 = e5 * r5;  const float r6 = r5 * K2;
                const float e7 = e6 * r6;
                union { half8 v; fp16x2 h[4]; } af;
                af.h[0] = __builtin_amdgcn_cvt_pkrtz(e0, e1);
                af.h[1] = __builtin_amdgcn_cvt_pkrtz(e2, e3);
                af.h[2] = __builtin_amdgcn_cvt_pkrtz(e4, e5);
                af.h[3] = __builtin_amdgcn_cvt_pkrtz(e6, e7);
                if (j & 1)
                    acc1 = __builtin_amdgcn_mfma_f32_16x16x32_f16(af.v, buf[j], acc1, 0, 0, 0);
                else
                    acc0 = __builtin_amdgcn_mfma_f32_16x16x32_f16(af.v, buf[j], acc0, 0, 0, 0);
            }
        };

        half8 bufA[GRP], bufB[GRP];
#pragma unroll
        for (int j = 0; j < GRP; ++j)
            bufA[j] = gp[(size_t)j * 64];

#pragma unroll 1
        for (int g = 0; g < NGRP; g += 2) {
            {   // prefetch group g+1 into bufB
                const half8* pn = gp + (size_t)(g + 1) * GRP * 64;
#pragma unroll
                for (int j = 0; j < GRP; ++j)
                    bufB[j] = pn[(size_t)j * 64];
            }
            compute_grp(g, bufA);
            if (g + 2 < NGRP) {   // prefetch group g+2 into bufA
                const half8* pn = gp + (size_t)(g + 2) * GRP * 64;
#pragma unroll
                for (int j = 0; j < GRP; ++j)
                    bufA[j] = pn[(size_t)j * 64];
            }
            compute_grp(g + 1, bufB);
        }

        if (m < 8) {
            float* pp = partial + (size_t)chunk * OUT_ELEMS
                      + ((size_t)(z * NPTS + a0 + quad * 4)) * DOUT + m;
#pragma unroll
            for (int r = 0; r < 4; ++r)
                pp[r * DOUT] = acc0[r] + acc1[r];
        }
    }
    __threadfence();
    cg::this_grid().sync();

    // ================= phase 3: reduce (blocks 0..255) =================
    if (bid < 256) {
        const int tx = t & 15;
        const int ty = t >> 4;
        const int e4 = bid * 16 + tx;
        const float4* p = (const float4*)partial;

        float4 s = make_float4(0.f, 0.f, 0.f, 0.f);
        // NCHUNK=16 -> exactly one chunk per ty
        {
            float4 v = p[(size_t)ty * NE4 + e4];
            s.x += v.x; s.y += v.y; s.z += v.z; s.w += v.w;
        }

        __shared__ float4 red[16][16];
        red[ty][tx] = s;
        __syncthreads();

        if (ty == 0) {
            float4 tot = red[0][tx];
#pragma unroll
            for (int j = 1; j < 16; ++j) {
                float4 v = red[j][tx];
                tot.x += v.x; tot.y += v.y; tot.z += v.z; tot.w += v.w;
            }
            const float scale = 1.0f / sqrtf((float)n_norm[0]);
            ((float4*)out)[e4] = make_float4(tot.x * scale, tot.y * scale,
                                             tot.z * scale, tot.w * scale);
        }
    }
}

// ---------------------------------------------------------------------------
extern "C" void kernel_launch(void* const* d_in, const int* in_sizes, int n_in,
                              void* d_out, int out_size, void* d_ws, size_t ws_size,
                              hipStream_t stream) {
    const float* feat   = (const float*)d_in[0];   // [2,1024,8]
    const float* geo    = (const float*)d_in[1];   // [2,1024,3]
    const float* W      = (const float*)d_in[2];   // [32,8,8]
    const int*   n_norm = (const int*)  d_in[3];   // scalar 1024
    float* out = (float*)d_out;                    // [2,1024,8]

    half8* gws     = (half8*)d_ws;                              // 2 MB
    float* partial = (float*)((char*)d_ws + G_BYTES);           // 1 MB

    void* args[] = { (void*)&feat, (void*)&geo, (void*)&W, (void*)&n_norm,
                     (void*)&out, (void*)&gws, (void*)&partial };
    hipLaunchCooperativeKernel((const void*)fused, dim3(NBLK), dim3(256),
                               args, 0, stream);
}

// Round 17
// 77.061 us; speedup vs baseline: 3.3383x; 3.3383x over previous
//
#include <hip/hip_runtime.h>
#include <math.h>

#define BATCH 2
#define NPTS  1024
#define NC    32
#define DIN   8
#define DOUT  8
#define ATILE 64                          // a's per block (4 waves x 16)
#define NCHUNK 64                         // b-splits -> 2048 blocks, 8/CU
#define BPW   (NPTS / NCHUNK)             // 16 b's per block
#define OUT_ELEMS (BATCH * NPTS * DOUT)   // 16384
#define NE4   (OUT_ELEMS / 4)             // 4096
#define LOG2E 1.4426950408889634f
#define G_BYTES ((size_t)BATCH * NPTS * 64 * 16)   // 2 MB of half8 B-frags

typedef _Float16 half8 __attribute__((ext_vector_type(8)));
typedef __fp16   fp16x2 __attribute__((ext_vector_type(2)));
typedef float    floatx4 __attribute__((ext_vector_type(4)));

#if __has_builtin(__builtin_amdgcn_exp2f)
#define EXP2F(x) __builtin_amdgcn_exp2f(x)
#else
#define EXP2F(x) exp2f(x)
#endif

// ---------------------------------------------------------------------------
// g_kernel (unchanged, R11..R15-verified): one-time build of B-frags in ws.
// ---------------------------------------------------------------------------
__global__ __launch_bounds__(256) void g_kernel(
        const float* __restrict__ feat,
        const float* __restrict__ W,
        half8*       __restrict__ gws) {
    const int e    = blockIdx.x * 256 + threadIdx.x;  // < BATCH*NPTS*64
    const int slot = e & 63;
    const int zb   = e >> 6;
    half8 gv = {};
    if (!(slot & 8)) {
        const int i   = slot & 7;
        const int oct = slot >> 4;
        const float* f = feat + (size_t)zb * DIN;
        const float4 f0 = *(const float4*)f;
        const float4 f1 = *(const float4*)(f + 4);
#pragma unroll
        for (int j = 0; j < 8; ++j) {
            const float* wr = W + ((oct * 8 + j) * DOUT + i) * DIN;
            const float4 wa = *(const float4*)wr;
            const float4 wb = *(const float4*)(wr + 4);
            float s = fmaf(wa.x, f0.x,
                      fmaf(wa.y, f0.y,
                      fmaf(wa.z, f0.z,
                      fmaf(wa.w, f0.w,
                      fmaf(wb.x, f1.x,
                      fmaf(wb.y, f1.y,
                      fmaf(wb.z, f1.z,
                             wb.w * f1.w)))))));
            gv[j] = (_Float16)s;
        }
    }
    gws[e] = gv;
}

// ---------------------------------------------------------------------------
// conv_mfma v8 — OCCUPANCY, finally for real. Session ledger: every round ran
// at <=2-3 waves/SIMD (R6/R14/R16 counters: 17-23% occupancy from 2-blocks/CU
// grids; R12/R13/R15 were VGPR-capped under launch_bounds(256,2)'s 256-VGPR
// allowance). A latency-bound body at 2 waves/SIMD explains the invariant
// ~28us across all structures. This round: launch_bounds(256,6) -> VGPR<=84
// -> 6 waves/SIMD allowed; B-frags in LDS (zero VGPR, staged by a 4-dwordx4
// per-thread copy from gws); 2048 blocks = 8/CU supply; unroll 4 bounds
// register hoisting. Math/layouts byte-identical to R12/R15 (verified).
// ---------------------------------------------------------------------------
__global__ __launch_bounds__(256, 6) void conv_mfma(
        const float* __restrict__ geo,
        const half8* __restrict__ gws,
        float*       __restrict__ partial) {  // [NCHUNK][BATCH*NPTS][DOUT]
    __shared__ half8 gl[BPW * 64];            // 16 KB B-frags

    const int t     = threadIdx.x;
    const int bid   = blockIdx.x;
    const int chunk = bid & (NCHUNK - 1);
    const int atile = (bid >> 6) & 15;
    const int z     = bid >> 10;

    const int b0 = chunk * BPW;
    const float* geoz = geo + (size_t)z * NPTS * 3;
    const float* bge  = geoz + b0 * 3;         // wave-uniform base

    // ---- stage the chunk's B-frags: 16 KB, 4 x dwordx4 per thread ----
    {
        const uint4* src = (const uint4*)(gws + ((size_t)(z * NPTS + b0)) * 64);
        uint4* dst = (uint4*)gl;
#pragma unroll
        for (int j = 0; j < 4; ++j)
            dst[t + 256 * j] = src[t + 256 * j];
    }
    __syncthreads();

    const int lane = t & 63;
    const int wv   = t >> 6;
    const int m    = lane & 15;
    const int quad = lane >> 4;
    const int a0   = atile * ATILE + wv * 16;
    const int a    = a0 + m;

    const float ax = geoz[a * 3 + 0];
    const float ay = geoz[a * 3 + 1];
    const float az = geoz[a * 3 + 2];
    const float c0   = (float)(quad * 8);
    const float invw = (float)(NC - 1) / 3.5f;
    const float K2   = 0.13533528324f;         // exp(-2)
    const float K8   = 3.35462627903e-4f;      // exp(-8)

    floatx4 acc0 = {0.f, 0.f, 0.f, 0.f};
    floatx4 acc1 = {0.f, 0.f, 0.f, 0.f};

#pragma unroll 4
    for (int b = 0; b < BPW; ++b) {
        // wave-uniform geo -> s_loads, batched per unroll window
        const float bx = bge[b * 3 + 0];
        const float by = bge[b * 3 + 1];
        const float bz = bge[b * 3 + 2];
        const float dx = bx - ax, dy = by - ay, dz = bz - az;
        const float u  = sqrtf(fmaf(dx, dx, fmaf(dy, dy, fmaf(dz, dz, 1e-12f)))) * invw;
        const float tc = fminf(u - c0, 11.0f);
        // dual-seed recurrence (R12-verified, NaN-proof)
        const float e0 = EXP2F((tc * tc) * (-LOG2E));
        const float t4 = tc - 4.0f;
        const float e4 = EXP2F((t4 * t4) * (-LOG2E));
        const float r0 = EXP2F(fmaf(2.0f * LOG2E, tc, -LOG2E));   // exp(2tc-1)
        const float r4 = r0 * K8;
        const float e1 = e0 * r0;  const float r1 = r0 * K2;
        const float e2 = e1 * r1;  const float r2 = r1 * K2;
        const float e3 = e2 * r2;
        const float e5 = e4 * r4;  const float r5 = r4 * K2;
        const float e6 = e5 * r5;  const float r6 = r5 * K2;
        const float e7 = e6 * r6;
        union { half8 v; fp16x2 h[4]; } af;
        af.h[0] = __builtin_amdgcn_cvt_pkrtz(e0, e1);
        af.h[1] = __builtin_amdgcn_cvt_pkrtz(e2, e3);
        af.h[2] = __builtin_amdgcn_cvt_pkrtz(e4, e5);
        af.h[3] = __builtin_amdgcn_cvt_pkrtz(e6, e7);
        const half8 bfrg = gl[b * 64 + lane];  // ds_read_b128, zero VGPR cost at rest
        if (b & 1)
            acc1 = __builtin_amdgcn_mfma_f32_16x16x32_f16(af.v, bfrg, acc1, 0, 0, 0);
        else
            acc0 = __builtin_amdgcn_mfma_f32_16x16x32_f16(af.v, bfrg, acc0, 0, 0, 0);
    }

    // ---- epilogue: D col = i (lane&15, keep <8), row = quad*4 + reg ----
    if (m < 8) {
        float* pp = partial + (size_t)chunk * OUT_ELEMS
                  + ((size_t)(z * NPTS + a0 + quad * 4)) * DOUT + m;
#pragma unroll
        for (int r = 0; r < 4; ++r)
            pp[r * DOUT] = acc0[r] + acc1[r];
    }
}

// ---------------------------------------------------------------------------
// reduce_partials (R12-verified): 256 blocks, 16 f4-elems x 16 chunk-groups.
// ---------------------------------------------------------------------------
template <int NCH>
__global__ __launch_bounds__(256) void reduce_partials(
        const float* __restrict__ partial,
        const int*   __restrict__ n_norm,
        float*       __restrict__ out) {
    const int tx = threadIdx.x & 15;
    const int ty = threadIdx.x >> 4;
    const int e4 = blockIdx.x * 16 + tx;
    const float4* p = (const float4*)partial;

    float4 s = make_float4(0.f, 0.f, 0.f, 0.f);
#pragma unroll
    for (int j = 0; j < NCH / 16; ++j) {
        float4 v = p[(size_t)(j * 16 + ty) * NE4 + e4];
        s.x += v.x; s.y += v.y; s.z += v.z; s.w += v.w;
    }

    __shared__ float4 red[16][16];
    red[ty][tx] = s;
    __syncthreads();

    if (ty == 0) {
        float4 tot = red[0][tx];
#pragma unroll
        for (int j = 1; j < 16; ++j) {
            float4 v = red[j][tx];
            tot.x += v.x; tot.y += v.y; tot.z += v.z; tot.w += v.w;
        }
        const float scale = 1.0f / sqrtf((float)n_norm[0]);
        ((float4*)out)[e4] = make_float4(tot.x * scale, tot.y * scale,
                                         tot.z * scale, tot.w * scale);
    }
}

// ---------------------------------------------------------------------------
extern "C" void kernel_launch(void* const* d_in, const int* in_sizes, int n_in,
                              void* d_out, int out_size, void* d_ws, size_t ws_size,
                              hipStream_t stream) {
    const float* feat   = (const float*)d_in[0];   // [2,1024,8]
    const float* geo    = (const float*)d_in[1];   // [2,1024,3]
    const float* W      = (const float*)d_in[2];   // [32,8,8]
    const int*   n_norm = (const int*)  d_in[3];   // scalar 1024
    float* out = (float*)d_out;                    // [2,1024,8]

    half8* gws     = (half8*)d_ws;                              // 2 MB
    float* partial = (float*)((char*)d_ws + G_BYTES);           // 4 MB

    g_kernel<<<(BATCH * NPTS * 64) / 256, 256, 0, stream>>>(feat, W, gws);
    conv_mfma<<<BATCH * 16 * NCHUNK, 256, 0, stream>>>(geo, gws, partial);
    reduce_partials<NCHUNK><<<NE4 / 16, 256, 0, stream>>>(partial, n_norm, out);
}